// Round 19
// baseline (313.834 us; speedup 1.0000x reference)
//
#include <hip/hip_runtime.h>

#define NN 100000
#define NE 1600000
#define F_IN 165
#define KP0 192       // F_IN padded (layer-0 K bound)
#define HDIM 128
#define BMG 64        // GEMM row-block
#define BK 64         // layer-0 K-step
#define NT_H 1563     // ceil(NN/64) row-tiles for persistent gemm
#define PGRID 512     // persistent gemm grid (2 blocks/CU, all resident)
#define CAP 48        // neighbor slots per node
#define ZROW NN       // dummy zero row index in p8
#define ZB (NN << 7)  // pre-shifted byte offset of zero row (128B rows)
#define NBIN 13       // ceil(NN / 8192)
#define ABLK 1024     // phase-A blocks
#define SEGC 256      // per block-bin segment capacity
#define NSUB 64       // sub-bins per bin (128 nodes each)
#define SLICES 32     // rebin slices per bin
#define CAP2 128      // pairs2 per-(sub,slice) capacity

typedef float f32x4 __attribute__((ext_vector_type(4)));
typedef __bf16 bf16x8 __attribute__((ext_vector_type(8)));
typedef unsigned long long u64;

static inline int ceil_div(int a, int b) { return (a + b - 1) / b; }

__device__ inline unsigned short f2bf(float f) {
    union { float f; unsigned u; } c; c.f = f;
    unsigned u = c.u;
    u += 0x7FFFu + ((u >> 16) & 1u);   // round-to-nearest-even
    return (unsigned short)(u >> 16);
}
__device__ inline float blo(unsigned v) {
    union { unsigned u; float f; } c; c.u = v << 16; return c.f;
}
__device__ inline float bhi(unsigned v) {
    union { unsigned u; float f; } c; c.u = v & 0xffff0000u; return c.f;
}
__device__ inline unsigned pack2(float f0, float f1) {
    return (unsigned)f2bf(f0) | ((unsigned)f2bf(f1) << 16);
}

// async global->LDS, 16B per lane; ldsbase must be WAVE-UNIFORM (HW adds lane*16)
__device__ __forceinline__ void gload16(const void* gsrc, char* ldsbase) {
    __builtin_amdgcn_global_load_lds(
        (const __attribute__((address_space(1))) unsigned*)gsrc,
        (__attribute__((address_space(3))) unsigned*)ldsbase, 16, 0, 0);
}

// ---------------- adjacency build, phase A: dense LDS binning ----------------

__global__ __launch_bounds__(256) void bin_edges(const int* __restrict__ src,
                                                 const int* __restrict__ dst,
                                                 unsigned* __restrict__ pairs,
                                                 int* __restrict__ pcnt, int E) {
    __shared__ unsigned buf[NBIN][SEGC];
    __shared__ int bcnt[NBIN];
    if (threadIdx.x < NBIN) bcnt[threadIdx.x] = 0;
    __syncthreads();
    const int per = (E + ABLK - 1) / ABLK;
    const int beg = blockIdx.x * per, end = min(beg + per, E);
    for (int e = beg + threadIdx.x; e < end; e += 256) {
        int d = __builtin_nontemporal_load(&dst[e]);
        int s = __builtin_nontemporal_load(&src[e]);
        int b = d >> 13;
        int pos = atomicAdd(&bcnt[b], 1);
        if (pos < SEGC) buf[b][pos] = (unsigned)s | ((unsigned)(d & 8191) << 17);
    }
    __syncthreads();
    for (int b = 0; b < NBIN; b++) {
        int cnt = min(bcnt[b], SEGC);
        if (threadIdx.x < cnt)
            pairs[(((size_t)b << 10) + blockIdx.x) * SEGC + threadIdx.x] = buf[b][threadIdx.x];
        if (threadIdx.x == 0) pcnt[(b << 10) + blockIdx.x] = cnt;
    }
}

// ---------------- phase B: re-bin to 128-node sub-bins ----------------

__global__ __launch_bounds__(256) void rebin(const unsigned* __restrict__ pairs,
                                             const int* __restrict__ pcnt,
                                             unsigned* __restrict__ pairs2,
                                             int* __restrict__ cnt2) {
    __shared__ unsigned buf[NSUB][CAP2];   // 32 KB
    __shared__ int bcnt[NSUB];
    const int bin = blockIdx.x >> 5;
    const int slice = blockIdx.x & 31;
    if (threadIdx.x < NSUB) bcnt[threadIdx.x] = 0;
    __syncthreads();
    for (int sg = 0; sg < 32; sg++) {
        int seg = (bin << 10) + slice * 32 + sg;
        int cnt = pcnt[seg];
        if (threadIdx.x < cnt) {
            unsigned v = pairs[((size_t)seg << 8) + threadIdx.x];
            int dl = (int)(v >> 17);
            int sub = dl >> 7;
            int pos = atomicAdd(&bcnt[sub], 1);
            if (pos < CAP2)
                buf[sub][pos] = (v & 0x1FFFFu) | ((unsigned)(dl & 127) << 17);
        }
    }
    __syncthreads();
    for (int sub = 0; sub < NSUB; sub++) {
        int cnt = min(bcnt[sub], CAP2);
        if (threadIdx.x < cnt)
            pairs2[(((size_t)(bin * NSUB + sub)) * SLICES + slice) * CAP2 + threadIdx.x] =
                buf[sub][threadIdx.x];
        if (threadIdx.x == 0) cnt2[(bin * NSUB + sub) * SLICES + slice] = cnt;
    }
}

// ---------------- phase C: compose 128-node slot rows ----------------

__global__ __launch_bounds__(256) void slots_dense(const unsigned* __restrict__ pairs2,
                                                   const int* __restrict__ cnt2,
                                                   int* __restrict__ dcount,
                                                   int* __restrict__ colb) {
    __shared__ int rowbuf[128 * CAP];      // 24 KB
    __shared__ int cur[128];
    const int bin = blockIdx.x >> 6;
    const int sub = blockIdx.x & 63;
    const int node0 = (bin << 13) + (sub << 7);

    int4* rb4 = (int4*)rowbuf;
    int4 z4 = {ZB, ZB, ZB, ZB};
    for (int i = threadIdx.x; i < 128 * CAP / 4; i += 256) rb4[i] = z4;
    if (threadIdx.x < 128) cur[threadIdx.x] = 0;
    __syncthreads();

    for (int slice = 0; slice < SLICES; slice++) {
        int base = (bin * NSUB + sub) * SLICES + slice;
        int cnt = cnt2[base];
        if (threadIdx.x < cnt) {
            unsigned v = pairs2[(size_t)base * CAP2 + threadIdx.x];
            int nl = (int)(v >> 17);
            int slot = atomicAdd(&cur[nl], 1);
            if (slot < CAP) rowbuf[nl * CAP + slot] = (int)((v & 0x1FFFFu) << 7);
        }
    }
    __syncthreads();

    if (threadIdx.x < 128 && node0 + threadIdx.x < NN)
        dcount[node0 + threadIdx.x] = cur[threadIdx.x];

    int4* col4 = (int4*)colb;
    const int IPR = CAP / 4;
    for (int idx = threadIdx.x; idx < 128 * IPR; idx += 256) {
        int row = idx / IPR, c4 = idx - row * IPR;
        if (node0 + row < NN)
            col4[(size_t)(node0 + row) * IPR + c4] = rb4[idx];
    }
}

// ---------------- zero row init ----------------

__global__ void zero_zrow(u64* __restrict__ p8_64, float* __restrict__ scales) {
    if (threadIdx.x < 16) p8_64[(size_t)ZROW * 16 + threadIdx.x] = 0x8080808080808080ull;
    if (threadIdx.x == 0) scales[ZROW] = 1.f;
}

// ---------------- weight conversion (layer 0, row-major padded) ----------------

__global__ void convert_w(const float* __restrict__ Wl0, const float* __restrict__ Wr0,
                          unsigned short* __restrict__ wb) {
    int w = blockIdx.x >> 7, row = blockIdx.x & 127, k = threadIdx.x;  // 192 threads
    const float* W = w ? Wr0 : Wl0;
    wb[(size_t)(w * 128 + row) * KP0 + k] =
        (k < F_IN) ? f2bf(W[row * F_IN + k]) : (unsigned short)0;
}

// ---------------- weight conversion (layers 1/2, k-major tiled for persistent gemm) ----------------
// Layout: wbf2[layer][c][t][u]*16B, u = g*16+lr holds W[(t&7)*16+lr][c*32+g*8 .. +8]
// (t<8 -> Wl (P cols), t>=8 -> Wr (Q cols)). Linear wave-gload of 1KB => coalesced,
// and LDS fragment reads at (g*16+lr)*16 are consecutive-16B-per-lane (conflict-free).

__global__ void convert_w2(const float* __restrict__ Wl1, const float* __restrict__ Wr1,
                           const float* __restrict__ Wl2, const float* __restrict__ Wr2,
                           char* __restrict__ wbf2) {
    const int layer = blockIdx.x >> 6;
    const int c = (blockIdx.x >> 4) & 3;
    const int t = blockIdx.x & 15;
    const int u = threadIdx.x;             // 64 threads
    const int lr = u & 15, g = u >> 4;
    const float* W = (t < 8) ? (layer ? Wl2 : Wl1) : (layer ? Wr2 : Wr1);
    const int row = (t & 7) * 16 + lr;
    unsigned short o[8];
#pragma unroll
    for (int e = 0; e < 8; e++) o[e] = f2bf(W[row * HDIM + c * 32 + g * 8 + e]);
    *(int4*)(wbf2 + (size_t)layer * 65536 + c * 16384 + t * 1024 + u * 16) = *(int4*)o;
}

// ---------------- layer-0 GEMM (f32 input, K=192): R14 structure ----------------

__global__ __launch_bounds__(256) void gemm_dual_l0(
    const float* __restrict__ xf, const unsigned short* __restrict__ Wcat,
    const float* __restrict__ bias, unsigned char* __restrict__ Yp8,
    float* __restrict__ scales, unsigned short* __restrict__ Yq, int n) {
    __shared__ char Asb[8192];
    __shared__ char Wsb[32768];
    const int tid = threadIdx.x;
    const int lane = tid & 63;
    const int wv = tid >> 6;
    const int row0 = blockIdx.x * BMG;
    const int lr = lane & 15;
    const int g = lane >> 4;
    const int kl = g * 8;
    const int Kp = KP0;

    f32x4 accP[8] = {};
    f32x4 accQ[8] = {};

    int4 ra0, ra1;
    auto loadA_f32 = [&](int k0) {
#pragma unroll
        for (int sI = 0; sI < 2; sI++) {
            int s = sI * 256 + tid;
            int c = s >> 8, rem = s & 255;
            int row = rem >> 2, kk = c * 32 + (rem & 3) * 8;
            int grow = row0 + row, kb = k0 + kk;
            unsigned short o[8];
            if (grow < n && kb < F_IN) {
                if (kb + 8 <= F_IN) {
                    f32x4 f0 = *(const f32x4*)&xf[(size_t)grow * F_IN + kb];
                    f32x4 f1 = *(const f32x4*)&xf[(size_t)grow * F_IN + kb + 4];
#pragma unroll
                    for (int t = 0; t < 4; t++) { o[t] = f2bf(f0[t]); o[4 + t] = f2bf(f1[t]); }
                } else {
#pragma unroll
                    for (int t = 0; t < 8; t++) {
                        int k = kb + t;
                        o[t] = (k < F_IN) ? f2bf(xf[(size_t)grow * F_IN + k]) : (unsigned short)0;
                    }
                }
            } else {
#pragma unroll
                for (int t = 0; t < 8; t++) o[t] = 0;
            }
            if (sI == 0) ra0 = *(int4*)o; else ra1 = *(int4*)o;
        }
    };

    loadA_f32(0);

    const int nsteps = Kp / BK;            // 3
    for (int st = 0; st < nsteps; st++) {
        const int k0 = st * BK;
        __syncthreads();
        *(int4*)(Asb + (size_t)tid * 16) = ra0;
        *(int4*)(Asb + (size_t)(256 + tid) * 16) = ra1;
#pragma unroll
        for (int w = 0; w < 8; w++) {
            int c = w & 1;
            int rg16 = wv * 4 + (w >> 1);
            int grow = rg16 * 16 + (lane >> 2);
            int gcol = k0 + c * 32 + (lane & 3) * 8;
            gload16(&Wcat[(size_t)grow * Kp + gcol], Wsb + c * 16384 + rg16 * 1024);
        }
        __syncthreads();
        if (st + 1 < nsteps) loadA_f32(k0 + BK);

#pragma unroll
        for (int c = 0; c < 2; c++) {
            bf16x8 af = *(const bf16x8*)(Asb + c * 4096 + (wv * 16 + lr) * 64 + kl * 2);
#pragma unroll
            for (int ct = 0; ct < 8; ct++) {
                bf16x8 bvP = *(const bf16x8*)(Wsb + c * 16384 + (ct * 16 + lr) * 64 + kl * 2);
                bf16x8 bvQ = *(const bf16x8*)(Wsb + c * 16384 + (128 + ct * 16 + lr) * 64 + kl * 2);
                accP[ct] = __builtin_amdgcn_mfma_f32_16x16x32_bf16(af, bvP, accP[ct], 0, 0, 0);
                accQ[ct] = __builtin_amdgcn_mfma_f32_16x16x32_bf16(af, bvQ, accQ[ct], 0, 0, 0);
            }
        }
    }

    // epilogue: Q -> bf16; P -> per-row int8 + scale (LDS stage in Wsb)
    __syncthreads();
    char* stage = Wsb;
    const int lrow_g = g * 4;
#pragma unroll
    for (int ct = 0; ct < 8; ct++) {
        int col = ct * 16 + lr;
        float b = bias[col];
#pragma unroll
        for (int r = 0; r < 4; r++) {
            int row = row0 + wv * 16 + lrow_g + r;
            if (row < n) Yq[(size_t)row * HDIM + col] = f2bf(accQ[ct][r] + b);
        }
    }
#pragma unroll
    for (int r = 0; r < 4; r++) {
        float m = 0.f;
#pragma unroll
        for (int ct = 0; ct < 8; ct++) m = fmaxf(m, fabsf(accP[ct][r]));
#pragma unroll
        for (int mk = 1; mk < 16; mk <<= 1) m = fmaxf(m, __shfl_xor(m, mk, 64));
        float inv = 127.f / fmaxf(m, 1e-30f);
        int lrow = wv * 16 + lrow_g + r;
#pragma unroll
        for (int ct = 0; ct < 8; ct++) {
            unsigned u = (unsigned)(accP[ct][r] * inv + 128.5f);
            stage[lrow * 144 + ct * 16 + lr] = (char)u;
        }
        if (lr == 0) {
            int row = row0 + lrow;
            if (row < n) scales[row] = m * (1.f / 127.f);
        }
    }
#pragma unroll
    for (int k = 0; k < 2; k++) {
        int unit = k * 64 + lane;
        int lrow = unit >> 3, chunk = unit & 7;
        int row = row0 + wv * 16 + lrow;
        int4 vv = *(const int4*)&stage[(wv * 16 + lrow) * 144 + chunk * 16];
        if (row < n) *(int4*)&Yp8[(size_t)row * 128 + chunk * 16] = vv;
    }
}

// ---------------- persistent GEMM (layers 1/2, K=128) ----------------
// W (64KB, pre-arranged k-major) loaded ONCE into LDS (coalesced 1KB wave-gloads),
// then zero-barrier grid-stride loop over 64-row tiles: A direct global->reg,
// 64 MFMA from read-only LDS (conflict-free), wave-local epilogue (no LDS stage:
// p8 packed to u32 via 2x shfl_xor). 512 blocks = 2/CU, all resident, no tail.

__global__ __launch_bounds__(256) void gemm_persist(
    const unsigned short* __restrict__ Xb, const char* __restrict__ Wt,
    const float* __restrict__ bias, unsigned char* __restrict__ Yp8,
    float* __restrict__ scales, unsigned short* __restrict__ Yq, int n, int ntiles) {
    __shared__ char lds[65536];
    const int tid = threadIdx.x;
    const int lane = tid & 63;
    const int wv = tid >> 6;
    const int lr = lane & 15;
    const int g = lane >> 4;

    // load all of W: wave wv loads chunk c=wv (16 KB = 16 x 1KB tiles), linear+coalesced
#pragma unroll
    for (int i = 0; i < 16; i++) {
        int off = wv * 16384 + i * 1024;
        gload16(Wt + off + lane * 16, lds + off);
    }
    __syncthreads();   // single drain; LDS read-only hereafter

    for (int t = blockIdx.x; t < ntiles; t += gridDim.x) {
        const int rowbase = t * 64 + wv * 16;
        const int myrow = rowbase + lr;

        bf16x8 af[4];
#pragma unroll
        for (int c = 0; c < 4; c++) {
            int4 v = {0, 0, 0, 0};
            if (myrow < n) v = *(const int4*)&Xb[(size_t)myrow * HDIM + c * 32 + g * 8];
            af[c] = *(const bf16x8*)&v;
        }

        f32x4 accP[8] = {};
        f32x4 accQ[8] = {};
#pragma unroll
        for (int ct = 0; ct < 8; ct++)
#pragma unroll
            for (int c = 0; c < 4; c++) {
                bf16x8 bvP = *(const bf16x8*)(lds + c * 16384 + ct * 1024 + (g * 16 + lr) * 16);
                bf16x8 bvQ = *(const bf16x8*)(lds + c * 16384 + (8 + ct) * 1024 + (g * 16 + lr) * 16);
                accP[ct] = __builtin_amdgcn_mfma_f32_16x16x32_bf16(af[c], bvP, accP[ct], 0, 0, 0);
                accQ[ct] = __builtin_amdgcn_mfma_f32_16x16x32_bf16(af[c], bvQ, accQ[ct], 0, 0, 0);
            }

        // ---- wave-local epilogue (no barriers) ----
#pragma unroll
        for (int ct = 0; ct < 8; ct++) {
            int col = ct * 16 + lr;
            float b = bias[col];
#pragma unroll
            for (int r = 0; r < 4; r++) {
                int row = rowbase + g * 4 + r;
                if (row < n) Yq[(size_t)row * HDIM + col] = f2bf(accQ[ct][r] + b);
            }
        }
#pragma unroll
        for (int r = 0; r < 4; r++) {
            int row = rowbase + g * 4 + r;
            float m = 0.f;
#pragma unroll
            for (int ct = 0; ct < 8; ct++) m = fmaxf(m, fabsf(accP[ct][r]));
#pragma unroll
            for (int mk = 1; mk < 16; mk <<= 1) m = fmaxf(m, __shfl_xor(m, mk, 64));
            float inv = 127.f / fmaxf(m, 1e-30f);
            if (lr == 0 && row < n) scales[row] = m * (1.f / 127.f);
#pragma unroll
            for (int ct = 0; ct < 8; ct++) {
                unsigned byte = (unsigned)(accP[ct][r] * inv + 128.5f) & 0xffu;
                unsigned u = byte << ((lr & 3) * 8);
                u |= __shfl_xor(u, 1, 64);
                u |= __shfl_xor(u, 2, 64);
                if ((lr & 3) == 0 && row < n)
                    *(unsigned*)&Yp8[(size_t)row * 128 + ct * 16 + lr] = u;
            }
        }
    }
}

// ---------------- aggregation + epilogue: 2 nodes/wave, int8 gather, zero-row padded ----------------

template <int MODE>
__global__ __launch_bounds__(256) void aggregate_w2(
    const unsigned char* __restrict__ p8, const float* __restrict__ scales,
    const unsigned* __restrict__ q32, const unsigned* __restrict__ r32,
    unsigned* __restrict__ hout32, const int* __restrict__ dcount,
    const int* __restrict__ colb, const float* __restrict__ Wlin,
    const float* __restrict__ blin, float* __restrict__ out) {
    const int lane = threadIdx.x & 63;
    const int wv = threadIdx.x >> 6;
    const int iA = blockIdx.x * 8 + wv * 2;
    const int iB = iA + 1;
    const int half = lane >> 5;
    const int fl = lane & 31;
    const int i = half ? iB : iA;
    const char* pb = (const char*)p8;

    const int degA = dcount[iA], degB = dcount[iB];
    const int c0 = colb[(size_t)i * CAP + fl];
    const int c1 = (fl < 16) ? colb[(size_t)i * CAP + 32 + fl] : ZB;
    const float sc0 = scales[(unsigned)c0 >> 7];
    const float sc1 = scales[(unsigned)c1 >> 7];
    const int hb4 = (lane & 32) << 2;
    const int fl4 = fl << 2;

    const int tpad = (min(max(degA, degB), CAP) + 7) & ~7;

    float a0 = 0.f, a1 = 0.f, a2 = 0.f, a3 = 0.f, ssum = 0.f;

#define GATHERN(N, CREG, SREG, SOFF)                                            \
    {                                                                           \
        unsigned v[N];                                                          \
        float sv[N];                                                            \
        _Pragma("unroll")                                                       \
        for (int t = 0; t < N; t++) {                                           \
            int idx = hb4 + ((SOFF + t) << 2);                                  \
            int off = __builtin_amdgcn_ds_bpermute(idx, CREG);                  \
            sv[t] = __int_as_float(__builtin_amdgcn_ds_bpermute(idx, __float_as_int(SREG))); \
            v[t] = *(const unsigned*)(pb + (size_t)(unsigned)off + fl4);        \
        }                                                                       \
        _Pragma("unroll")                                                       \
        for (int t = 0; t < N; t++) {                                           \
            float s = sv[t];                                                    \
            a0 += s * (float)(v[t] & 0xffu);                                    \
            a1 += s * (float)((v[t] >> 8) & 0xffu);                             \
            a2 += s * (float)((v[t] >> 16) & 0xffu);                            \
            a3 += s * (float)(v[t] >> 24);                                      \
            ssum += s;                                                          \
        }                                                                       \
    }

    const int t1 = min(tpad, 32);
    int j = 0;
    for (; j + 16 <= t1; j += 16) GATHERN(16, c0, sc0, j)
    if (j < t1) GATHERN(8, c0, sc0, j)
    if (tpad > 40)      GATHERN(16, c1, sc1, 0)
    else if (tpad > 32) GATHERN(8, c1, sc1, 0)
#undef GATHERN

    const float s128 = 128.f * ssum;
    a0 -= s128; a1 -= s128; a2 -= s128; a3 -= s128;

    const int deg = half ? degB : degA;
    const float inv = 1.f / fmaxf((float)deg, 1.f);
    u64 qv = __builtin_nontemporal_load((const u64*)&q32[((size_t)i << 6) + (fl << 1)]);
    unsigned qlo = (unsigned)qv, qhi = (unsigned)(qv >> 32);
    float v0 = a0 * inv + blo(qlo);
    float v1 = a1 * inv + bhi(qlo);
    float v2 = a2 * inv + blo(qhi);
    float v3 = a3 * inv + bhi(qhi);

    auto wsum32 = [&](float x) -> float {
        for (int off = 16; off > 0; off >>= 1) x += __shfl_xor(x, off, 64);
        return x;
    };

    if (MODE == 0) {
        u64 o = (u64)pack2(fmaxf(v0, 0.f), fmaxf(v1, 0.f)) |
                ((u64)pack2(fmaxf(v2, 0.f), fmaxf(v3, 0.f)) << 32);
        __builtin_nontemporal_store(o, (u64*)&hout32[((size_t)i << 6) + (fl << 1)]);
        return;
    }

    u64 rv = __builtin_nontemporal_load((const u64*)&r32[((size_t)i << 6) + (fl << 1)]);
    unsigned rlo = (unsigned)rv, rhi = (unsigned)(rv >> 32);
    v0 += blo(rlo); v1 += bhi(rlo); v2 += blo(rhi); v3 += bhi(rhi);
    float mu = wsum32(v0 + v1 + v2 + v3) * (1.f / HDIM);
    float d0 = v0 - mu, d1 = v1 - mu, d2 = v2 - mu, d3 = v3 - mu;
    float var = wsum32(d0 * d0 + d1 * d1 + d2 * d2 + d3 * d3) * (1.f / HDIM);
    float rs = rsqrtf(var + 1e-5f);
    float h0 = fmaxf(d0 * rs, 0.f);
    float h1 = fmaxf(d1 * rs, 0.f);
    float h2 = fmaxf(d2 * rs, 0.f);
    float h3 = fmaxf(d3 * rs, 0.f);

    if (MODE == 1) {
        u64 o = (u64)pack2(h0, h1) | ((u64)pack2(h2, h3) << 32);
        __builtin_nontemporal_store(o, (u64*)&hout32[((size_t)i << 6) + (fl << 1)]);
    } else {
        const float4* wlv = (const float4*)Wlin;
        float4 w0 = wlv[fl];
        float4 w1 = wlv[32 + fl];
        float s0 = wsum32(h0 * w0.x + h1 * w0.y + h2 * w0.z + h3 * w0.w);
        float s1 = wsum32(h0 * w1.x + h1 * w1.y + h2 * w1.z + h3 * w1.w);
        if (fl == 0) {
            out[(size_t)i * 2 + 0] = s0 + blin[0];
            out[(size_t)i * 2 + 1] = s1 + blin[1];
        }
    }
}

// ---------------- launch ----------------

static inline size_t rnd(size_t x) { return (x + 255) & ~(size_t)255; }

extern "C" void kernel_launch(void* const* d_in, const int* in_sizes, int n_in,
                              void* d_out, int out_size, void* d_ws, size_t ws_size,
                              hipStream_t stream) {
    const float* x = (const float*)d_in[0];
    const int* ei = (const int*)d_in[1];
    const int* srcI = ei;
    const int* dstI = ei + NE;
    const float* Wl0 = (const float*)d_in[2];
    const float* bl0 = (const float*)d_in[3];
    const float* Wr0 = (const float*)d_in[4];
    const float* Wl1 = (const float*)d_in[5];
    const float* bl1 = (const float*)d_in[6];
    const float* Wr1 = (const float*)d_in[7];
    const float* Wl2 = (const float*)d_in[8];
    const float* bl2 = (const float*)d_in[9];
    const float* Wr2 = (const float*)d_in[10];
    const float* Wlin = (const float*)d_in[11];
    const float* blin = (const float*)d_in[12];
    float* out = (float*)d_out;

    // workspace carve (256B-aligned)
    char* w = (char*)d_ws;
    unsigned char* p8 = (unsigned char*)w;      w += rnd((size_t)(NN + 1) * 128);
    float* scales = (float*)w;                  w += rnd((size_t)(NN + 1) * 4);
    unsigned short* q = (unsigned short*)w;     w += rnd((size_t)NN * HDIM * 2);
    unsigned short* hbfA = (unsigned short*)w;  w += rnd((size_t)NN * HDIM * 2);
    unsigned short* hbfB = (unsigned short*)w;  w += rnd((size_t)NN * HDIM * 2);
    unsigned short* wbf = (unsigned short*)w;   w += rnd((size_t)256 * KP0 * 2);
    char* wbf2 = (char*)w;                      w += rnd((size_t)2 * 65536);
    int* dcount = (int*)w;  w += rnd((size_t)NN * 4);
    int* colb = (int*)w;    w += rnd((size_t)NN * CAP * 4 + 256);

    // pairs/pcnt alias q; pairs2/cnt2 alias hbfA (dead until after build)
    unsigned* pairs = (unsigned*)q;
    int* pcnt = (int*)(pairs + (size_t)NBIN * 1024 * SEGC);
    unsigned* pairs2 = (unsigned*)hbfA;
    int* cnt2 = (int*)(pairs2 + (size_t)NBIN * NSUB * SLICES * CAP2);

    // adjacency build (3-phase radix by dst)
    zero_zrow<<<1, 64, 0, stream>>>((u64*)p8, scales);
    bin_edges<<<ABLK, 256, 0, stream>>>(srcI, dstI, pairs, pcnt, NE);
    rebin<<<NBIN * SLICES, 256, 0, stream>>>(pairs, pcnt, pairs2, cnt2);
    slots_dense<<<NBIN * NSUB, 256, 0, stream>>>(pairs2, cnt2, dcount, colb);

    convert_w<<<2 * 128, 192, 0, stream>>>(Wl0, Wr0, wbf);
    convert_w2<<<128, 64, 0, stream>>>(Wl1, Wr1, Wl2, Wr2, wbf2);

    const int GB = ceil_div(NN, BMG);
    const int AG = ceil_div(NN, 8);

    // layer 0
    gemm_dual_l0<<<GB, 256, 0, stream>>>(x, wbf, bl0, p8, scales, q, NN);
    aggregate_w2<0><<<AG, 256, 0, stream>>>(p8, scales, (const unsigned*)q, nullptr,
                                            (unsigned*)hbfA, dcount, colb, nullptr, nullptr, nullptr);

    // layer 1 (persistent)
    gemm_persist<<<PGRID, 256, 0, stream>>>(hbfA, wbf2, bl1, p8, scales, q, NN, NT_H);
    aggregate_w2<1><<<AG, 256, 0, stream>>>(p8, scales, (const unsigned*)q, (const unsigned*)hbfA,
                                            (unsigned*)hbfB, dcount, colb, nullptr, nullptr, nullptr);

    // layer 2 (persistent) + final proj
    gemm_persist<<<PGRID, 256, 0, stream>>>(hbfB, wbf2 + 65536, bl2, p8, scales, q, NN, NT_H);
    aggregate_w2<2><<<AG, 256, 0, stream>>>(p8, scales, (const unsigned*)q, (const unsigned*)hbfB,
                                            nullptr, dcount, colb, Wlin, blin, out);
}

// Round 20
// 288.009 us; speedup vs baseline: 1.0897x; 1.0897x over previous
//
#include <hip/hip_runtime.h>

#define NN 100000
#define NE 1600000
#define F_IN 165
#define KP0 192       // F_IN padded (layer-0 K bound)
#define HDIM 128
#define BMG 64        // GEMM row-block (1563 blocks)
#define BK 64         // K-step (2 chunk-major 32k sub-tiles)
#define CAP 48        // neighbor slots per node
#define ZROW NN       // dummy zero row index in p8
#define ZB (NN << 7)  // pre-shifted byte offset of zero row (128B rows)
#define NBIN 13       // ceil(NN / 8192)
#define ABLK 1024     // phase-A blocks
#define SEGC 256      // per block-bin segment capacity
#define NSUB 64       // sub-bins per bin (128 nodes each)
#define SLICES 32     // rebin slices per bin
#define CAP2 128      // pairs2 per-(sub,slice) capacity

typedef float f32x4 __attribute__((ext_vector_type(4)));
typedef __bf16 bf16x8 __attribute__((ext_vector_type(8)));
typedef unsigned long long u64;

static inline int ceil_div(int a, int b) { return (a + b - 1) / b; }

__device__ inline unsigned short f2bf(float f) {
    union { float f; unsigned u; } c; c.f = f;
    unsigned u = c.u;
    u += 0x7FFFu + ((u >> 16) & 1u);   // round-to-nearest-even
    return (unsigned short)(u >> 16);
}
__device__ inline float blo(unsigned v) {
    union { unsigned u; float f; } c; c.u = v << 16; return c.f;
}
__device__ inline float bhi(unsigned v) {
    union { unsigned u; float f; } c; c.u = v & 0xffff0000u; return c.f;
}
__device__ inline unsigned pack2(float f0, float f1) {
    return (unsigned)f2bf(f0) | ((unsigned)f2bf(f1) << 16);
}

// async global->LDS, 16B per lane; ldsbase must be WAVE-UNIFORM (HW adds lane*16)
__device__ __forceinline__ void gload16(const void* gsrc, char* ldsbase) {
    __builtin_amdgcn_global_load_lds(
        (const __attribute__((address_space(1))) unsigned*)gsrc,
        (__attribute__((address_space(3))) unsigned*)ldsbase, 16, 0, 0);
}

// ---------------- adjacency build, phase A: dense LDS binning ----------------
// (also initializes p8's zero row + its scale -- saves a separate launch)

__global__ __launch_bounds__(256) void bin_edges(const int* __restrict__ src,
                                                 const int* __restrict__ dst,
                                                 unsigned* __restrict__ pairs,
                                                 int* __restrict__ pcnt,
                                                 u64* __restrict__ p8_64,
                                                 float* __restrict__ scales, int E) {
    __shared__ unsigned buf[NBIN][SEGC];
    __shared__ int bcnt[NBIN];
    if (blockIdx.x == 0) {
        if (threadIdx.x < 16) p8_64[(size_t)ZROW * 16 + threadIdx.x] = 0x8080808080808080ull;
        if (threadIdx.x == 16) scales[ZROW] = 1.f;
    }
    if (threadIdx.x < NBIN) bcnt[threadIdx.x] = 0;
    __syncthreads();
    const int per = (E + ABLK - 1) / ABLK;
    const int beg = blockIdx.x * per, end = min(beg + per, E);
    for (int e = beg + threadIdx.x; e < end; e += 256) {
        int d = __builtin_nontemporal_load(&dst[e]);
        int s = __builtin_nontemporal_load(&src[e]);
        int b = d >> 13;
        int pos = atomicAdd(&bcnt[b], 1);
        if (pos < SEGC) buf[b][pos] = (unsigned)s | ((unsigned)(d & 8191) << 17);
    }
    __syncthreads();
    for (int b = 0; b < NBIN; b++) {
        int cnt = min(bcnt[b], SEGC);
        if (threadIdx.x < cnt)
            pairs[(((size_t)b << 10) + blockIdx.x) * SEGC + threadIdx.x] = buf[b][threadIdx.x];
        if (threadIdx.x == 0) pcnt[(b << 10) + blockIdx.x] = cnt;
    }
}

// ---------------- phase B: re-bin to 128-node sub-bins ----------------

__global__ __launch_bounds__(256) void rebin(const unsigned* __restrict__ pairs,
                                             const int* __restrict__ pcnt,
                                             unsigned* __restrict__ pairs2,
                                             int* __restrict__ cnt2) {
    __shared__ unsigned buf[NSUB][CAP2];   // 32 KB
    __shared__ int bcnt[NSUB];
    const int bin = blockIdx.x >> 5;
    const int slice = blockIdx.x & 31;
    if (threadIdx.x < NSUB) bcnt[threadIdx.x] = 0;
    __syncthreads();
    for (int sg = 0; sg < 32; sg++) {
        int seg = (bin << 10) + slice * 32 + sg;
        int cnt = pcnt[seg];
        if (threadIdx.x < cnt) {
            unsigned v = pairs[((size_t)seg << 8) + threadIdx.x];
            int dl = (int)(v >> 17);
            int sub = dl >> 7;
            int pos = atomicAdd(&bcnt[sub], 1);
            if (pos < CAP2)
                buf[sub][pos] = (v & 0x1FFFFu) | ((unsigned)(dl & 127) << 17);
        }
    }
    __syncthreads();
    for (int sub = 0; sub < NSUB; sub++) {
        int cnt = min(bcnt[sub], CAP2);
        if (threadIdx.x < cnt)
            pairs2[(((size_t)(bin * NSUB + sub)) * SLICES + slice) * CAP2 + threadIdx.x] =
                buf[sub][threadIdx.x];
        if (threadIdx.x == 0) cnt2[(bin * NSUB + sub) * SLICES + slice] = cnt;
    }
}

// ---------------- phase C: compose 128-node slot rows ----------------

__global__ __launch_bounds__(256) void slots_dense(const unsigned* __restrict__ pairs2,
                                                   const int* __restrict__ cnt2,
                                                   int* __restrict__ dcount,
                                                   int* __restrict__ colb) {
    __shared__ int rowbuf[128 * CAP];      // 24 KB
    __shared__ int cur[128];
    const int bin = blockIdx.x >> 6;
    const int sub = blockIdx.x & 63;
    const int node0 = (bin << 13) + (sub << 7);

    int4* rb4 = (int4*)rowbuf;
    int4 z4 = {ZB, ZB, ZB, ZB};
    for (int i = threadIdx.x; i < 128 * CAP / 4; i += 256) rb4[i] = z4;
    if (threadIdx.x < 128) cur[threadIdx.x] = 0;
    __syncthreads();

    for (int slice = 0; slice < SLICES; slice++) {
        int base = (bin * NSUB + sub) * SLICES + slice;
        int cnt = cnt2[base];
        if (threadIdx.x < cnt) {
            unsigned v = pairs2[(size_t)base * CAP2 + threadIdx.x];
            int nl = (int)(v >> 17);
            int slot = atomicAdd(&cur[nl], 1);
            if (slot < CAP) rowbuf[nl * CAP + slot] = (int)((v & 0x1FFFFu) << 7);
        }
    }
    __syncthreads();

    if (threadIdx.x < 128 && node0 + threadIdx.x < NN)
        dcount[node0 + threadIdx.x] = cur[threadIdx.x];

    int4* col4 = (int4*)colb;
    const int IPR = CAP / 4;
    for (int idx = threadIdx.x; idx < 128 * IPR; idx += 256) {
        int row = idx / IPR, c4 = idx - row * IPR;
        if (node0 + row < NN)
            col4[(size_t)(node0 + row) * IPR + c4] = rb4[idx];
    }
}

// ---------------- weight conversion ----------------

__global__ void convert_w(const float* __restrict__ Wl0, const float* __restrict__ Wr0,
                          const float* __restrict__ Wl1, const float* __restrict__ Wr1,
                          const float* __restrict__ Wl2, const float* __restrict__ Wr2,
                          unsigned short* __restrict__ wb) {
    int w = blockIdx.x >> 7, row = blockIdx.x & 127, k = threadIdx.x;  // 192 threads
    const size_t base1 = (size_t)256 * KP0;
    const size_t base2 = base1 + (size_t)256 * HDIM;
    if (w < 2) {
        const float* W = w ? Wr0 : Wl0;
        wb[(size_t)(w * 128 + row) * KP0 + k] =
            (k < F_IN) ? f2bf(W[row * F_IN + k]) : (unsigned short)0;
    } else if (k < HDIM) {
        const float* W = (w == 2) ? Wl1 : (w == 3) ? Wr1 : (w == 4) ? Wl2 : Wr2;
        int layer = (w - 2) >> 1, half = (w - 2) & 1;
        size_t base = layer ? base2 : base1;
        wb[base + (size_t)(half * 128 + row) * HDIM + k] = f2bf(W[row * HDIM + k]);
    }
}

// ---------------- dual MFMA GEMM: global_load_lds pipeline, BK=64 chunk-major ----------------
// (R14 structure, best measured: 293.4 us total)

template <bool XF32>
__global__ __launch_bounds__(256) void gemm_dual(
    const void* __restrict__ Xv, const unsigned short* __restrict__ Wcat,
    const float* __restrict__ bias, unsigned char* __restrict__ Yp8,
    float* __restrict__ scales, unsigned short* __restrict__ Yq, int n, int Kp) {
    __shared__ __bf16 As[2 * 64 * 32];     // 8 KB
    __shared__ __bf16 Ws[2 * 256 * 32];    // 32 KB (aliased as stage in epilogue)
    const int tid = threadIdx.x;
    const int lane = tid & 63;
    const int wv = tid >> 6;
    const int row0 = blockIdx.x * BMG;
    const int lr = lane & 15;
    const int g = lane >> 4;
    const int kl = g * 8;

    f32x4 accP[8] = {};
    f32x4 accQ[8] = {};

    int4 ra0, ra1;
    auto loadA_f32 = [&](int k0) {
        const float* xf = (const float*)Xv;
#pragma unroll
        for (int sI = 0; sI < 2; sI++) {
            int s = sI * 256 + tid;
            int c = s >> 8, rem = s & 255;
            int row = rem >> 2, kk = c * 32 + (rem & 3) * 8;
            int grow = row0 + row, kb = k0 + kk;
            unsigned short o[8];
            if (grow < n && kb < F_IN) {
                if (kb + 8 <= F_IN) {
                    f32x4 f0 = *(const f32x4*)&xf[(size_t)grow * F_IN + kb];
                    f32x4 f1 = *(const f32x4*)&xf[(size_t)grow * F_IN + kb + 4];
#pragma unroll
                    for (int t = 0; t < 4; t++) { o[t] = f2bf(f0[t]); o[4 + t] = f2bf(f1[t]); }
                } else {
#pragma unroll
                    for (int t = 0; t < 8; t++) {
                        int k = kb + t;
                        o[t] = (k < F_IN) ? f2bf(xf[(size_t)grow * F_IN + k]) : (unsigned short)0;
                    }
                }
            } else {
#pragma unroll
                for (int t = 0; t < 8; t++) o[t] = 0;
            }
            if (sI == 0) ra0 = *(int4*)o; else ra1 = *(int4*)o;
        }
    };

    if (XF32) loadA_f32(0);

    const int nsteps = Kp / BK;
    for (int st = 0; st < nsteps; st++) {
        const int k0 = st * BK;
        __syncthreads();   // previous step's ds_reads done -> LDS reusable

        if (XF32) {
            *(int4*)((char*)As + (size_t)tid * 16) = ra0;
            *(int4*)((char*)As + (size_t)(256 + tid) * 16) = ra1;
        } else {
            const unsigned short* Xb = (const unsigned short*)Xv;
#pragma unroll
            for (int c = 0; c < 2; c++) {
                int grow = row0 + wv * 16 + (lane >> 2);
                int gcol = k0 + c * 32 + (lane & 3) * 8;
                gload16(&Xb[(size_t)grow * Kp + gcol], (char*)As + c * 4096 + wv * 1024);
            }
        }
#pragma unroll
        for (int w = 0; w < 8; w++) {
            int c = w & 1;
            int rg16 = wv * 4 + (w >> 1);
            int grow = rg16 * 16 + (lane >> 2);
            int gcol = k0 + c * 32 + (lane & 3) * 8;
            gload16(&Wcat[(size_t)grow * Kp + gcol], (char*)Ws + c * 16384 + rg16 * 1024);
        }
        __syncthreads();   // drain gloads + A ds_writes

        if (XF32 && st + 1 < nsteps) loadA_f32(k0 + BK);   // fly during MFMA

#pragma unroll
        for (int c = 0; c < 2; c++) {
            bf16x8 af = *(const bf16x8*)&As[c * 2048 + (wv * 16 + lr) * 32 + kl];
#pragma unroll
            for (int ct = 0; ct < 8; ct++) {
                bf16x8 bvP = *(const bf16x8*)&Ws[c * 8192 + (ct * 16 + lr) * 32 + kl];
                bf16x8 bvQ = *(const bf16x8*)&Ws[c * 8192 + (128 + ct * 16 + lr) * 32 + kl];
                accP[ct] = __builtin_amdgcn_mfma_f32_16x16x32_bf16(af, bvP, accP[ct], 0, 0, 0);
                accQ[ct] = __builtin_amdgcn_mfma_f32_16x16x32_bf16(af, bvQ, accQ[ct], 0, 0, 0);
            }
        }
    }

    // ---- epilogue: Q -> bf16; P -> per-row int8 + f32 scale ----
    __syncthreads();                       // all ds_reads done -> Ws reusable
    char* stage = (char*)Ws;               // 64 rows x 144B stride
    const int lrow_g = g * 4;

#pragma unroll
    for (int ct = 0; ct < 8; ct++) {
        int col = ct * 16 + lr;
        float b = bias ? bias[col] : 0.f;
#pragma unroll
        for (int r = 0; r < 4; r++) {
            int row = row0 + wv * 16 + lrow_g + r;
            if (row < n) Yq[(size_t)row * HDIM + col] = f2bf(accQ[ct][r] + b);
        }
    }

#pragma unroll
    for (int r = 0; r < 4; r++) {
        float m = 0.f;
#pragma unroll
        for (int ct = 0; ct < 8; ct++) m = fmaxf(m, fabsf(accP[ct][r]));
#pragma unroll
        for (int mk = 1; mk < 16; mk <<= 1) m = fmaxf(m, __shfl_xor(m, mk, 64));
        float inv = 127.f / fmaxf(m, 1e-30f);
        float sc = m * (1.f / 127.f);
        int lrow = wv * 16 + lrow_g + r;
#pragma unroll
        for (int ct = 0; ct < 8; ct++) {
            unsigned u = (unsigned)(accP[ct][r] * inv + 128.5f);
            stage[lrow * 144 + ct * 16 + lr] = (char)u;
        }
        if (lr == 0) {
            int row = row0 + wv * 16 + lrow_g + r;
            if (row < n) scales[row] = sc;
        }
    }
    // wave-local reload -> dense 16B stores
#pragma unroll
    for (int k = 0; k < 2; k++) {
        int unit = k * 64 + lane;          // 16 rows x 8 chunks
        int lrow = unit >> 3, chunk = unit & 7;
        int row = row0 + wv * 16 + lrow;
        int4 vv = *(const int4*)&stage[(wv * 16 + lrow) * 144 + chunk * 16];
        if (row < n) *(int4*)&Yp8[(size_t)row * 128 + chunk * 16] = vv;
    }
}

// ---------------- aggregation + epilogue: 2 nodes/wave, int8 gather, zero-row padded ----------------

template <int MODE>
__global__ __launch_bounds__(256) void aggregate_w2(
    const unsigned char* __restrict__ p8, const float* __restrict__ scales,
    const unsigned* __restrict__ q32, const unsigned* __restrict__ r32,
    unsigned* __restrict__ hout32, const int* __restrict__ dcount,
    const int* __restrict__ colb, const float* __restrict__ Wlin,
    const float* __restrict__ blin, float* __restrict__ out) {
    const int lane = threadIdx.x & 63;
    const int wv = threadIdx.x >> 6;
    const int iA = blockIdx.x * 8 + wv * 2;
    const int iB = iA + 1;
    const int half = lane >> 5;
    const int fl = lane & 31;
    const int i = half ? iB : iA;
    const char* pb = (const char*)p8;

    const int degA = dcount[iA], degB = dcount[iB];
    const int c0 = colb[(size_t)i * CAP + fl];
    const int c1 = (fl < 16) ? colb[(size_t)i * CAP + 32 + fl] : ZB;
    const float sc0 = scales[(unsigned)c0 >> 7];
    const float sc1 = scales[(unsigned)c1 >> 7];
    const int hb4 = (lane & 32) << 2;
    const int fl4 = fl << 2;

    const int tpad = (min(max(degA, degB), CAP) + 7) & ~7;

    float a0 = 0.f, a1 = 0.f, a2 = 0.f, a3 = 0.f, ssum = 0.f;

#define GATHERN(N, CREG, SREG, SOFF)                                            \
    {                                                                           \
        unsigned v[N];                                                          \
        float sv[N];                                                            \
        _Pragma("unroll")                                                       \
        for (int t = 0; t < N; t++) {                                           \
            int idx = hb4 + ((SOFF + t) << 2);                                  \
            int off = __builtin_amdgcn_ds_bpermute(idx, CREG);                  \
            sv[t] = __int_as_float(__builtin_amdgcn_ds_bpermute(idx, __float_as_int(SREG))); \
            v[t] = *(const unsigned*)(pb + (size_t)(unsigned)off + fl4);        \
        }                                                                       \
        _Pragma("unroll")                                                       \
        for (int t = 0; t < N; t++) {                                           \
            float s = sv[t];                                                    \
            a0 += s * (float)(v[t] & 0xffu);                                    \
            a1 += s * (float)((v[t] >> 8) & 0xffu);                             \
            a2 += s * (float)((v[t] >> 16) & 0xffu);                            \
            a3 += s * (float)(v[t] >> 24);                                      \
            ssum += s;                                                          \
        }                                                                       \
    }

    const int t1 = min(tpad, 32);
    int j = 0;
    for (; j + 16 <= t1; j += 16) GATHERN(16, c0, sc0, j)
    if (j < t1) GATHERN(8, c0, sc0, j)
    if (tpad > 40)      GATHERN(16, c1, sc1, 0)
    else if (tpad > 32) GATHERN(8, c1, sc1, 0)
#undef GATHERN

    const float s128 = 128.f * ssum;
    a0 -= s128; a1 -= s128; a2 -= s128; a3 -= s128;

    const int deg = half ? degB : degA;
    const float inv = 1.f / fmaxf((float)deg, 1.f);
    u64 qv = __builtin_nontemporal_load((const u64*)&q32[((size_t)i << 6) + (fl << 1)]);
    unsigned qlo = (unsigned)qv, qhi = (unsigned)(qv >> 32);
    float v0 = a0 * inv + blo(qlo);
    float v1 = a1 * inv + bhi(qlo);
    float v2 = a2 * inv + blo(qhi);
    float v3 = a3 * inv + bhi(qhi);

    auto wsum32 = [&](float x) -> float {
        for (int off = 16; off > 0; off >>= 1) x += __shfl_xor(x, off, 64);
        return x;
    };

    if (MODE == 0) {
        u64 o = (u64)pack2(fmaxf(v0, 0.f), fmaxf(v1, 0.f)) |
                ((u64)pack2(fmaxf(v2, 0.f), fmaxf(v3, 0.f)) << 32);
        __builtin_nontemporal_store(o, (u64*)&hout32[((size_t)i << 6) + (fl << 1)]);
        return;
    }

    u64 rv = __builtin_nontemporal_load((const u64*)&r32[((size_t)i << 6) + (fl << 1)]);
    unsigned rlo = (unsigned)rv, rhi = (unsigned)(rv >> 32);
    v0 += blo(rlo); v1 += bhi(rlo); v2 += blo(rhi); v3 += bhi(rhi);
    float mu = wsum32(v0 + v1 + v2 + v3) * (1.f / HDIM);
    float d0 = v0 - mu, d1 = v1 - mu, d2 = v2 - mu, d3 = v3 - mu;
    float var = wsum32(d0 * d0 + d1 * d1 + d2 * d2 + d3 * d3) * (1.f / HDIM);
    float rs = rsqrtf(var + 1e-5f);
    float h0 = fmaxf(d0 * rs, 0.f);
    float h1 = fmaxf(d1 * rs, 0.f);
    float h2 = fmaxf(d2 * rs, 0.f);
    float h3 = fmaxf(d3 * rs, 0.f);

    if (MODE == 1) {
        u64 o = (u64)pack2(h0, h1) | ((u64)pack2(h2, h3) << 32);
        __builtin_nontemporal_store(o, (u64*)&hout32[((size_t)i << 6) + (fl << 1)]);
    } else {
        const float4* wlv = (const float4*)Wlin;
        float4 w0 = wlv[fl];
        float4 w1 = wlv[32 + fl];
        float s0 = wsum32(h0 * w0.x + h1 * w0.y + h2 * w0.z + h3 * w0.w);
        float s1 = wsum32(h0 * w1.x + h1 * w1.y + h2 * w1.z + h3 * w1.w);
        if (fl == 0) {
            out[(size_t)i * 2 + 0] = s0 + blin[0];
            out[(size_t)i * 2 + 1] = s1 + blin[1];
        }
    }
}

// ---------------- launch ----------------

static inline size_t rnd(size_t x) { return (x + 255) & ~(size_t)255; }

extern "C" void kernel_launch(void* const* d_in, const int* in_sizes, int n_in,
                              void* d_out, int out_size, void* d_ws, size_t ws_size,
                              hipStream_t stream) {
    const float* x = (const float*)d_in[0];
    const int* ei = (const int*)d_in[1];
    const int* srcI = ei;
    const int* dstI = ei + NE;
    const float* Wl0 = (const float*)d_in[2];
    const float* bl0 = (const float*)d_in[3];
    const float* Wr0 = (const float*)d_in[4];
    const float* Wl1 = (const float*)d_in[5];
    const float* bl1 = (const float*)d_in[6];
    const float* Wr1 = (const float*)d_in[7];
    const float* Wl2 = (const float*)d_in[8];
    const float* bl2 = (const float*)d_in[9];
    const float* Wr2 = (const float*)d_in[10];
    const float* Wlin = (const float*)d_in[11];
    const float* blin = (const float*)d_in[12];
    float* out = (float*)d_out;

    // workspace carve (256B-aligned)
    char* w = (char*)d_ws;
    unsigned char* p8 = (unsigned char*)w;      w += rnd((size_t)(NN + 1) * 128);
    float* scales = (float*)w;                  w += rnd((size_t)(NN + 1) * 4);
    unsigned short* q = (unsigned short*)w;     w += rnd((size_t)NN * HDIM * 2);
    unsigned short* hbfA = (unsigned short*)w;  w += rnd((size_t)NN * HDIM * 2);
    unsigned short* hbfB = (unsigned short*)w;  w += rnd((size_t)NN * HDIM * 2);
    unsigned short* wbf = (unsigned short*)w;   w += rnd((size_t)(256 * KP0 + 2 * 256 * HDIM) * 2);
    int* dcount = (int*)w;  w += rnd((size_t)NN * 4);
    int* colb = (int*)w;    w += rnd((size_t)NN * CAP * 4 + 256);

    // pairs/pcnt alias q; pairs2/cnt2 alias hbfA (dead until after build)
    unsigned* pairs = (unsigned*)q;
    int* pcnt = (int*)(pairs + (size_t)NBIN * 1024 * SEGC);
    unsigned* pairs2 = (unsigned*)hbfA;
    int* cnt2 = (int*)(pairs2 + (size_t)NBIN * NSUB * SLICES * CAP2);

    // adjacency build (3-phase radix by dst); bin_edges also inits p8 zero row
    bin_edges<<<ABLK, 256, 0, stream>>>(srcI, dstI, pairs, pcnt, (u64*)p8, scales, NE);
    rebin<<<NBIN * SLICES, 256, 0, stream>>>(pairs, pcnt, pairs2, cnt2);
    slots_dense<<<NBIN * NSUB, 256, 0, stream>>>(pairs2, cnt2, dcount, colb);

    convert_w<<<6 * 128, 192, 0, stream>>>(Wl0, Wr0, Wl1, Wr1, Wl2, Wr2, wbf);

    const unsigned short* wb0 = wbf;
    const unsigned short* wb1 = wbf + (size_t)256 * KP0;
    const unsigned short* wb2 = wb1 + (size_t)256 * HDIM;

    const int GB = ceil_div(NN, BMG);
    const int AG = ceil_div(NN, 8);

    // layer 0 (f32 A reg-staged; W via global_load_lds)
    gemm_dual<true><<<GB, 256, 0, stream>>>(x, wb0, bl0, p8, scales, q, NN, KP0);
    aggregate_w2<0><<<AG, 256, 0, stream>>>(p8, scales, (const unsigned*)q, nullptr,
                                            (unsigned*)hbfA, dcount, colb, nullptr, nullptr, nullptr);

    // layer 1
    gemm_dual<false><<<GB, 256, 0, stream>>>(hbfA, wb1, bl1, p8, scales, q, NN, HDIM);
    aggregate_w2<1><<<AG, 256, 0, stream>>>(p8, scales, (const unsigned*)q, (const unsigned*)hbfA,
                                            (unsigned*)hbfB, dcount, colb, nullptr, nullptr, nullptr);

    // layer 2 + final proj
    gemm_dual<false><<<GB, 256, 0, stream>>>(hbfB, wb2, bl2, p8, scales, q, NN, HDIM);
    aggregate_w2<2><<<AG, 256, 0, stream>>>(p8, scales, (const unsigned*)q, (const unsigned*)hbfB,
                                            nullptr, dcount, colb, Wlin, blin, out);
}